// Round 9
// baseline (952.491 us; speedup 1.0000x reference)
//
#include <hip/hip_runtime.h>
#include <hip/hip_bf16.h>
#include <hip/hip_fp8.h>

typedef __bf16 bf16_t;
typedef bf16_t bf16x8 __attribute__((ext_vector_type(8)));
typedef float f32x4 __attribute__((ext_vector_type(4)));
typedef float f32x16 __attribute__((ext_vector_type(16)));
typedef int   i32x4  __attribute__((ext_vector_type(4)));
typedef int   i32x8  __attribute__((ext_vector_type(8)));

#define N_ROWS 4096
#define DIM    2048
#define VOCAB  65536
#define IGN    (-100)

// ---------------- MX-fp8 256x256 GEMM, BK=128 ------------------------------
#define BM 256
#define BN 256
#define BK 128            // fp8 elems (=bytes) per K-tile
#define NT (DIM / BK)     // 16 K-tiles
#define NUNITS (4 * NT)   // 64 stage units (16KB each)
#define SCALE1 0x7F7F7F7F // e8m0 = 127 -> 1.0 in every byte

#define GLOAD_LDS16(gp, lp)                                                  \
  __builtin_amdgcn_global_load_lds(                                          \
      (const __attribute__((address_space(1))) void*)(gp),                   \
      (__attribute__((address_space(3))) void*)(lp), 16, 0, 0)

// fp32 -> fp8 e4m3 (OCP) with pre-scale; 16 elems/thread/iter
__global__ __launch_bounds__(256)
void cvt_fp8(const float* __restrict__ src, unsigned char* __restrict__ dst,
             long n16, float scale) {
  long i = (long)blockIdx.x * 256 + threadIdx.x;
  long stride = (long)gridDim.x * 256;
  for (; i < n16; i += stride) {
    const float4* s = reinterpret_cast<const float4*>(src) + i * 4;
    union { unsigned char b[16]; i32x4 v; } o;
#pragma unroll
    for (int q = 0; q < 4; ++q) {
      float4 a = s[q];
      o.b[q * 4 + 0] = __hip_fp8_e4m3(a.x * scale).__x;
      o.b[q * 4 + 1] = __hip_fp8_e4m3(a.y * scale).__x;
      o.b[q * 4 + 2] = __hip_fp8_e4m3(a.z * scale).__x;
      o.b[q * 4 + 3] = __hip_fp8_e4m3(a.w * scale).__x;
    }
    *reinterpret_cast<i32x4*>(dst + i * 16) = o.v;
  }
}

// 256x256 tile, BK=128, 8 waves (2M x 4N, each 128x64 out), MX-fp8 MFMA
// (32x32x64, unity scales; C pre-scaled x8, undone via acc*0.125).
// LDS 128KB = 8 slots x 16KB; unit u of tile T: 0=A[k0:64], 1=B[k0:64],
// 2=A[k64:128], 3=B[k64:128]. FRAGMENT-ORDER unit layout (conflict-free):
// granule g (16B) -> slab=g>>7 (32-row group), chunk=(g>>5)&3 (16B k-group),
// row=g&31; LDS addr = slab*2048 + chunk*512 + row*16. Frag reads are
// lane-contiguous (l31*16) => 0 bank conflicts; staging writes are linear
// (global_load_lds) with the permutation folded into the SOURCE address.
// Stage schedule per tile: {ph0:4T+6, ph1:4T+9, ph2:4T+8, ph3:4T+11};
// vmcnt(6) at ph3 guarantees tile T+1 resident (FIFO). Prologue {0..5,7}.
__global__ __launch_bounds__(512, 2)
void lce_gemm_fp8(const unsigned char* __restrict__ E8,
                  const unsigned char* __restrict__ C8,
                  float* __restrict__ sumexp) {
  extern __shared__ unsigned char lds[];  // 131072
  const int tid = threadIdx.x;
  const int lane = tid & 63, wid = tid >> 6;
  const int wr = wid >> 2, wc = wid & 3;      // 2M x 4N waves
  const int l31 = lane & 31, lh = lane >> 5;

  // bijective XCD swizzle (nwg=4096, %8==0), row-tile fast for C reuse
  const int bid = blockIdx.x;
  const int wg = (bid & 7) * (((N_ROWS / BM) * (VOCAB / BN)) / 8) + (bid >> 3);
  const int brow = (wg & (N_ROWS / BM - 1)) * BM;
  const int bcol = (wg / (N_ROWS / BM)) * BN;

  // ---- staging: per-thread 2 granules of 16B ------------------------------
  const int g0 = wid * 64 + lane;         // granule 0..511
  const int g1 = 512 + g0;                // granule 512..1023
  const int prel0 = g0 * 16;              // wave-uniform base + lane*16
  const int prel1 = g1 * 16;
  auto mkgoff = [&](int g) {              // fragment-order -> global offset
    int slab = g >> 7, chunk = (g >> 5) & 3, r = g & 31;
    return (size_t)(slab * 32 + r) * DIM + (size_t)(chunk * 16);
  };
  const size_t goff0 = mkgoff(g0), goff1 = mkgoff(g1);

  const unsigned char* Ebase = E8 + (size_t)brow * DIM;
  const unsigned char* Cbase = C8 + (size_t)bcol * DIM;

  auto stage = [&](int ug) {   // ug = global unit index [0, NUNITS)
    const unsigned char* gb = ((ug & 1) ? Cbase : Ebase) +
                              (ug >> 2) * BK + ((ug >> 1) & 1) * 64;
    unsigned char* lb = lds + (ug & 7) * 16384;     // slot = ug mod 8
    GLOAD_LDS16(gb + goff0, lb + prel0);
    GLOAD_LDS16(gb + goff1, lb + prel1);
  };

  // ---- fragment read: slab s of unit U (rows s*32+l31, k-half lh) ---------
  auto read_frag = [&](const unsigned char* U, int s) -> i32x8 {
    const unsigned char* p = U + s * 2048 + lh * 1024 + l31 * 16;
    i32x4 lo = *reinterpret_cast<const i32x4*>(p);
    i32x4 hi = *reinterpret_cast<const i32x4*>(p + 512);
    return __builtin_shufflevector(lo, hi, 0, 1, 2, 3, 4, 5, 6, 7);
  };

  f32x16 acc[4][2];
#pragma unroll
  for (int mi = 0; mi < 4; ++mi)
#pragma unroll
    for (int ni = 0; ni < 2; ++ni)
#pragma unroll
      for (int r = 0; r < 16; ++r) acc[mi][ni][r] = 0.f;

  // ---- prologue -----------------------------------------------------------
  stage(0); stage(1); stage(2); stage(3); stage(4); stage(5); stage(7);
  asm volatile("s_waitcnt vmcnt(6)" ::: "memory");  // units 0..3 landed
  __builtin_amdgcn_s_barrier();

  i32x8 af[2], bfr[2];

  for (int T = 0; T < NT; ++T) {
    const unsigned char* base = lds + (T & 1) * 65536;
#pragma unroll
    for (int ph = 0; ph < 4; ++ph) {
      const int ks = ph >> 1, mq = ph & 1;
      const unsigned char* aU = base + ks * 32768;
      const unsigned char* bU = aU + 16384;
      if (mq == 0) {
#pragma unroll
        for (int ni = 0; ni < 2; ++ni)
          bfr[ni] = read_frag(bU, wc * 2 + ni);
#pragma unroll
        for (int mi = 0; mi < 2; ++mi)
          af[mi] = read_frag(aU, wr * 4 + mi);
      } else {
#pragma unroll
        for (int mi = 0; mi < 2; ++mi)
          af[mi] = read_frag(aU, wr * 4 + 2 + mi);
      }
      __builtin_amdgcn_sched_barrier(0);            // reads issue first
      const int sug = 4 * T + ((ph == 0) ? 6 : (ph == 1) ? 9 : (ph == 2) ? 8 : 11);
      if (sug < NUNITS) stage(sug);
      asm volatile("s_waitcnt lgkmcnt(0)" ::: "memory");
      __builtin_amdgcn_sched_barrier(0);
      __builtin_amdgcn_s_setprio(1);
#pragma unroll
      for (int mi = 0; mi < 2; ++mi)
#pragma unroll
        for (int ni = 0; ni < 2; ++ni)
          acc[mq * 2 + mi][ni] = __builtin_amdgcn_mfma_scale_f32_32x32x64_f8f6f4(
              af[mi], bfr[ni], acc[mq * 2 + mi][ni],
              0, 0,            // cbsz=fp8, blgp=fp8
              0, SCALE1,       // A: opsel 0, scale 1.0
              0, SCALE1);      // B: opsel 0, scale 1.0
      __builtin_amdgcn_s_setprio(0);
      if (ph == 3 && T < NT - 1) {
        if (T < NT - 2) asm volatile("s_waitcnt vmcnt(6)" ::: "memory");
        else            asm volatile("s_waitcnt vmcnt(0)" ::: "memory");
      }
      __builtin_amdgcn_s_barrier();
    }
  }

  // ---- epilogue: per-row sum of exp(logit) over 256 vocab cols ------------
  // 32x32 C/D: col = lane&31, row = (reg&3) + 8*(reg>>2) + 4*(lane>>5).
  // Undo the C*8 pre-scale: logit = acc * 0.125.
#pragma unroll
  for (int mi = 0; mi < 4; ++mi) {
    float p[16];
#pragma unroll
    for (int r = 0; r < 16; ++r)
      p[r] = __expf(acc[mi][0][r] * 0.125f) + __expf(acc[mi][1][r] * 0.125f);
#pragma unroll
    for (int m = 1; m < 32; m <<= 1)
#pragma unroll
      for (int r = 0; r < 16; ++r) p[r] += __shfl_xor(p[r], m, 64);
    if (l31 == 0) {
#pragma unroll
      for (int r = 0; r < 16; ++r) {
        const int row = brow + wr * 128 + mi * 32 + (r & 3) + 8 * (r >> 2) + 4 * lh;
        atomicAdd(&sumexp[row], p[r]);
      }
    }
  }
}

// ---------------- fallback path (fp32 reg-staged, 128^2 tile) --------------
#define FBM 128
#define FBN 128
#define FBK 64
#define FNK (DIM / FBK)
#define FTHREADS 512

__global__ __launch_bounds__(FTHREADS, 4)
void lce_gemm_f32(const float* __restrict__ E, const float* __restrict__ C,
                  float* __restrict__ sumexp) {
  extern __shared__ unsigned char lds[];
  const int tid  = threadIdx.x;
  const int brow = blockIdx.x * FBM;
  const int bcol = blockIdx.y * FBN;

  float4 ra[4], rb[4];
  auto ld = [&](int k0) {
#pragma unroll
    for (int i = 0; i < 4; ++i) {
      int f = tid + i * FTHREADS;
      int r = f >> 4;
      int c = (f & 15) << 2;
      ra[i] = *reinterpret_cast<const float4*>(&E[(size_t)(brow + r) * DIM + k0 + c]);
      rb[i] = *reinterpret_cast<const float4*>(&C[(size_t)(bcol + r) * DIM + k0 + c]);
    }
  };
  auto st = [&](int buf) {
    unsigned char* a = lds + buf * 32768;
    unsigned char* b = a + 16384;
#pragma unroll
    for (int i = 0; i < 4; ++i) {
      int f  = tid + i * FTHREADS;
      int r  = f >> 4;
      int cbb = (f & 15) << 3;
      int off = r * 128 + (cbb ^ ((r & 7) << 4));
      union { bf16_t h[4]; unsigned long long u; } pa, pb;
      pa.h[0] = (bf16_t)ra[i].x; pa.h[1] = (bf16_t)ra[i].y;
      pa.h[2] = (bf16_t)ra[i].z; pa.h[3] = (bf16_t)ra[i].w;
      pb.h[0] = (bf16_t)rb[i].x; pb.h[1] = (bf16_t)rb[i].y;
      pb.h[2] = (bf16_t)rb[i].z; pb.h[3] = (bf16_t)rb[i].w;
      *reinterpret_cast<unsigned long long*>(a + off) = pa.u;
      *reinterpret_cast<unsigned long long*>(b + off) = pb.u;
    }
  };

  f32x4 acc[4][2];
#pragma unroll
  for (int mi = 0; mi < 4; ++mi)
#pragma unroll
    for (int ni = 0; ni < 2; ++ni) acc[mi][ni] = (f32x4){0.f, 0.f, 0.f, 0.f};

  const int lane = tid & 63, wid = tid >> 6;
  const int wr = wid >> 2, wc = wid & 3;
  const int l15 = lane & 15, lg = lane >> 4;
  const int swz = (l15 & 7) << 4;

  auto comp = [&](int buf) {
    const unsigned char* a = lds + buf * 32768;
    const unsigned char* b = a + 16384;
#pragma unroll
    for (int kk = 0; kk < 2; ++kk) {
      const int cbase = (kk * 64 + lg * 16) ^ swz;
      bf16x8 af[4], bfr[2];
#pragma unroll
      for (int mi = 0; mi < 4; ++mi)
        af[mi] = *reinterpret_cast<const bf16x8*>(
            a + (wr * 64 + mi * 16 + l15) * 128 + cbase);
#pragma unroll
      for (int ni = 0; ni < 2; ++ni)
        bfr[ni] = *reinterpret_cast<const bf16x8*>(
            b + (wc * 32 + ni * 16 + l15) * 128 + cbase);
#pragma unroll
      for (int mi = 0; mi < 4; ++mi)
#pragma unroll
        for (int ni = 0; ni < 2; ++ni)
          acc[mi][ni] = __builtin_amdgcn_mfma_f32_16x16x32_bf16(
              af[mi], bfr[ni], acc[mi][ni], 0, 0, 0);
    }
  };

  ld(0);
  st(0);
  for (int kt = 0; kt < FNK; ++kt) {
    __syncthreads();
    if (kt + 1 < FNK) ld((kt + 1) * FBK);
    comp(kt & 1);
    if (kt + 1 < FNK) st((kt + 1) & 1);
  }

#pragma unroll
  for (int mi = 0; mi < 4; ++mi) {
    float p[4];
#pragma unroll
    for (int j = 0; j < 4; ++j)
      p[j] = __expf(acc[mi][0][j]) + __expf(acc[mi][1][j]);
#pragma unroll
    for (int m = 1; m < 16; m <<= 1)
#pragma unroll
      for (int j = 0; j < 4; ++j) p[j] += __shfl_xor(p[j], m, 64);
    if (l15 == 0) {
      int row = brow + wr * 64 + mi * 16 + lg * 4;
#pragma unroll
      for (int j = 0; j < 4; ++j) atomicAdd(&sumexp[row + j], p[j]);
    }
  }
}

// ---------------- exact fp32 target logit, one wave per row ----------------
__global__ __launch_bounds__(256)
void lce_tgt(const float* __restrict__ E, const float* __restrict__ C,
             const int* __restrict__ T, float* __restrict__ tgt) {
  int w = (int)((blockIdx.x * blockDim.x + threadIdx.x) >> 6);
  int lane = threadIdx.x & 63;
  if (w >= N_ROWS) return;
  int t = T[w];
  float s = 0.f;
  if (t != IGN) {
    const float4* er = reinterpret_cast<const float4*>(E + (size_t)w * DIM);
    const float4* cr = reinterpret_cast<const float4*>(C + (size_t)t * DIM);
#pragma unroll
    for (int i = 0; i < DIM / 4 / 64; ++i) {
      float4 a = er[lane + i * 64];
      float4 b = cr[lane + i * 64];
      s = fmaf(a.x, b.x, s); s = fmaf(a.y, b.y, s);
      s = fmaf(a.z, b.z, s); s = fmaf(a.w, b.w, s);
    }
#pragma unroll
    for (int m = 1; m < 64; m <<= 1) s += __shfl_xor(s, m, 64);
  }
  if (lane == 0) tgt[w] = s;
}

// ---------------- final scalar reduce --------------------------------------
__global__ __launch_bounds__(256)
void lce_finalize(const float* __restrict__ sumexp, const float* __restrict__ tgt,
                  const int* __restrict__ T, float* __restrict__ out) {
  int tid = threadIdx.x;
  float nll = 0.f, cnt = 0.f;
  for (int n = tid; n < N_ROWS; n += 256) {
    if (T[n] != IGN) {
      nll += logf(sumexp[n]) - tgt[n];
      cnt += 1.f;
    }
  }
#pragma unroll
  for (int m = 1; m < 64; m <<= 1) {
    nll += __shfl_xor(nll, m, 64);
    cnt += __shfl_xor(cnt, m, 64);
  }
  __shared__ float sn[4], sc[4];
  if ((tid & 63) == 0) { sn[tid >> 6] = nll; sc[tid >> 6] = cnt; }
  __syncthreads();
  if (tid == 0) {
    float a = 0.f, b = 0.f;
#pragma unroll
    for (int i = 0; i < 4; ++i) { a += sn[i]; b += sc[i]; }
    out[0] = a / fmaxf(b, 1.f);
  }
}

extern "C" void kernel_launch(void* const* d_in, const int* in_sizes, int n_in,
                              void* d_out, int out_size, void* d_ws, size_t ws_size,
                              hipStream_t stream) {
  const float* E = (const float*)d_in[0];
  const float* C = (const float*)d_in[1];
  const int*   T = (const int*)d_in[2];
  float* out = (float*)d_out;

  unsigned char* ws = (unsigned char*)d_ws;
  float* sumexp = (float*)ws;                        // 16 KB
  float* tgt    = (float*)(ws + 16384);              // 16 KB
  unsigned char* E8 = ws + 32768;                    // 8 MB
  unsigned char* C8 = E8 + (size_t)N_ROWS * DIM;     // 128 MB

  const size_t need = 32768 + (size_t)N_ROWS * DIM + (size_t)VOCAB * DIM;

  hipMemsetAsync(sumexp, 0, N_ROWS * sizeof(float), stream);

  if (ws_size >= need) {
    cvt_fp8<<<2048, 256, 0, stream>>>(E, E8, (long)N_ROWS * DIM / 16, 1.0f);
    cvt_fp8<<<2048, 256, 0, stream>>>(C, C8, (long)VOCAB * DIM / 16, 8.0f);
    lce_gemm_fp8<<<dim3((N_ROWS / BM) * (VOCAB / BN)), 512, 131072, stream>>>(E8, C8, sumexp);
  } else {
    lce_gemm_f32<<<dim3(N_ROWS / FBM, VOCAB / FBN), FTHREADS, 65536, stream>>>(E, C, sumexp);
  }

  lce_tgt<<<dim3((N_ROWS * 64) / 256), 256, 0, stream>>>(E, C, T, tgt);
  lce_finalize<<<dim3(1), 256, 0, stream>>>(sumexp, tgt, T, out);
}

// Round 10
// 866.933 us; speedup vs baseline: 1.0987x; 1.0987x over previous
//
#include <hip/hip_runtime.h>
#include <hip/hip_bf16.h>
#include <hip/hip_fp8.h>

typedef __bf16 bf16_t;
typedef bf16_t bf16x8 __attribute__((ext_vector_type(8)));
typedef float f32x4 __attribute__((ext_vector_type(4)));
typedef float f32x16 __attribute__((ext_vector_type(16)));
typedef int   i32x4  __attribute__((ext_vector_type(4)));
typedef int   i32x8  __attribute__((ext_vector_type(8)));

#define N_ROWS 4096
#define DIM    2048
#define VOCAB  65536
#define IGN    (-100)

// ---------------- MX-fp8 256x256 GEMM, BK=128 ------------------------------
#define BM 256
#define BN 256
#define BK 128            // fp8 elems (=bytes) per K-tile
#define NT (DIM / BK)     // 16 K-tiles
#define NUNITS (4 * NT)   // 64 stage units (16KB each)
#define SCALE1 0x7F7F7F7F // e8m0 = 127 -> 1.0 in every byte

#define GLOAD_LDS16(gp, lp)                                                  \
  __builtin_amdgcn_global_load_lds(                                          \
      (const __attribute__((address_space(1))) void*)(gp),                   \
      (__attribute__((address_space(3))) void*)(lp), 16, 0, 0)

// fp32 -> fp8 e4m3 (OCP) with pre-scale; 16 elems/thread/iter
__global__ __launch_bounds__(256)
void cvt_fp8(const float* __restrict__ src, unsigned char* __restrict__ dst,
             long n16, float scale) {
  long i = (long)blockIdx.x * 256 + threadIdx.x;
  long stride = (long)gridDim.x * 256;
  for (; i < n16; i += stride) {
    const float4* s = reinterpret_cast<const float4*>(src) + i * 4;
    union { unsigned char b[16]; i32x4 v; } o;
#pragma unroll
    for (int q = 0; q < 4; ++q) {
      float4 a = s[q];
      o.b[q * 4 + 0] = __hip_fp8_e4m3(a.x * scale).__x;
      o.b[q * 4 + 1] = __hip_fp8_e4m3(a.y * scale).__x;
      o.b[q * 4 + 2] = __hip_fp8_e4m3(a.z * scale).__x;
      o.b[q * 4 + 3] = __hip_fp8_e4m3(a.w * scale).__x;
    }
    *reinterpret_cast<i32x4*>(dst + i * 16) = o.v;
  }
}

// 256x256 tile, BK=128, 8 waves (2M x 4N, each 128x64 out), MX-fp8 MFMA
// (32x32x64, unity scales; C pre-scaled x8, undone via acc*0.125).
// LDS 128KB = 8 slots x 16KB; unit u of tile T: 0=A[k0:64], 1=B[k0:64],
// 2=A[k64:128], 3=B[k64:128]. Unit layout: 16 windows of 1KB, window w =
// rows 16w..16w+15. Within a window, slot i holds global granule
// tau(i) = (i&~3) | ((i&3) ^ ((i>>3)&3))  (self-inverse 64-slot perm).
// Staging: gload_lds linear dest + per-lane source (row i>>2, chunk
// (i&3)^((i>>3)&3)) -- the 64 lanes cover the SAME contiguous 16x64B
// region as row-major (perfect coalescing), lanes permuted. Reads: lane
// l31 reads row l31's chunk c at r16*64 + (c ^ ((l31>>1)&3))*16 --
// 8-lane groups hit 8 distinct 4-bank slots => conflict-free b128 both ways.
// 2 phases/tile (ks = k-half): {12 ds_read; stage 2 units; lgkm(0);
// 8 MFMA; [vmcnt]; barrier}. Stage schedule: P0 stages {4T+6,4T+7},
// P1 stages {4T+8,4T+9}; vmcnt(4) at P1 end (vmcnt(0) at T=NT-2)
// guarantees tile T+1's 4 units resident. Slot lifetimes verified:
// each slot overwritten >=1 barrier after its reads drained.
__global__ __launch_bounds__(512, 2)
void lce_gemm_fp8(const unsigned char* __restrict__ E8,
                  const unsigned char* __restrict__ C8,
                  float* __restrict__ sumexp) {
  extern __shared__ unsigned char lds[];  // 131072
  const int tid = threadIdx.x;
  const int lane = tid & 63, wid = tid >> 6;
  const int wr = wid >> 2, wc = wid & 3;      // 2M x 4N waves
  const int l31 = lane & 31, lh = lane >> 5;

  // bijective XCD swizzle (nwg=4096, %8==0), row-tile fast for C reuse
  const int bid = blockIdx.x;
  const int wg = (bid & 7) * (((N_ROWS / BM) * (VOCAB / BN)) / 8) + (bid >> 3);
  const int brow = (wg & (N_ROWS / BM - 1)) * BM;
  const int bcol = (wg / (N_ROWS / BM)) * BN;

  // ---- staging: per-thread 2 granules of 16B ------------------------------
  const int g0 = wid * 64 + lane;         // granule 0..511 (window = wid)
  const int g1 = 512 + g0;                // granule 512..1023
  const int prel0 = g0 * 16;              // linear LDS dest
  const int prel1 = g1 * 16;
  auto mkgoff = [&](int g) {              // window-permuted global source
    int w = g >> 6, i = g & 63;
    return (size_t)(w * 16 + (i >> 2)) * DIM +
           (size_t)((((i & 3) ^ ((i >> 3) & 3)) << 4));
  };
  const size_t goff0 = mkgoff(g0), goff1 = mkgoff(g1);

  const unsigned char* Ebase = E8 + (size_t)brow * DIM;
  const unsigned char* Cbase = C8 + (size_t)bcol * DIM;

  auto stage = [&](int ug) {   // ug = global unit index [0, NUNITS)
    const unsigned char* gb = ((ug & 1) ? Cbase : Ebase) +
                              (ug >> 2) * BK + ((ug >> 1) & 1) * 64;
    unsigned char* lb = lds + (ug & 7) * 16384;     // slot = ug mod 8
    GLOAD_LDS16(gb + goff0, lb + prel0);
    GLOAD_LDS16(gb + goff1, lb + prel1);
  };

  // ---- fragment read: slab s (rows s*32+l31), k-half lh, swizzled chunks --
  const int sw = (l31 >> 1) & 3;
  auto read_frag = [&](const unsigned char* U, int s) -> i32x8 {
    const unsigned char* p =
        U + s * 2048 + (l31 >> 4) * 1024 + (l31 & 15) * 64;
    i32x4 lo = *reinterpret_cast<const i32x4*>(p + (((lh * 2)     ^ sw) << 4));
    i32x4 hi = *reinterpret_cast<const i32x4*>(p + (((lh * 2 + 1) ^ sw) << 4));
    return __builtin_shufflevector(lo, hi, 0, 1, 2, 3, 4, 5, 6, 7);
  };

  f32x16 acc[4][2];
#pragma unroll
  for (int mi = 0; mi < 4; ++mi)
#pragma unroll
    for (int ni = 0; ni < 2; ++ni)
#pragma unroll
      for (int r = 0; r < 16; ++r) acc[mi][ni][r] = 0.f;

  // ---- prologue: units 0..5 in flight, first 4 landed ---------------------
  stage(0); stage(1); stage(2); stage(3); stage(4); stage(5);
  asm volatile("s_waitcnt vmcnt(4)" ::: "memory");  // units 0..3 landed
  __builtin_amdgcn_s_barrier();

  i32x8 af[4], bfr[2];

  for (int T = 0; T < NT; ++T) {
    const unsigned char* base = lds + (T & 1) * 65536;
#pragma unroll
    for (int ks = 0; ks < 2; ++ks) {
      const unsigned char* aU = base + ks * 32768;
      const unsigned char* bU = aU + 16384;
#pragma unroll
      for (int ni = 0; ni < 2; ++ni)
        bfr[ni] = read_frag(bU, wc * 2 + ni);
#pragma unroll
      for (int mi = 0; mi < 4; ++mi)
        af[mi] = read_frag(aU, wr * 4 + mi);
      __builtin_amdgcn_sched_barrier(0);            // reads issue first
      const int ug = 4 * T + 6 + ks * 2;
      if (ug < NUNITS) stage(ug);
      if (ug + 1 < NUNITS) stage(ug + 1);
      asm volatile("s_waitcnt lgkmcnt(0)" ::: "memory");
      __builtin_amdgcn_sched_barrier(0);
      __builtin_amdgcn_s_setprio(1);
#pragma unroll
      for (int mi = 0; mi < 4; ++mi)
#pragma unroll
        for (int ni = 0; ni < 2; ++ni)
          acc[mi][ni] = __builtin_amdgcn_mfma_scale_f32_32x32x64_f8f6f4(
              af[mi], bfr[ni], acc[mi][ni],
              0, 0,            // cbsz=fp8, blgp=fp8
              0, SCALE1,       // A: opsel 0, scale 1.0
              0, SCALE1);      // B: opsel 0, scale 1.0
      __builtin_amdgcn_s_setprio(0);
      if (ks == 1 && T < NT - 1) {
        if (T < NT - 2) asm volatile("s_waitcnt vmcnt(4)" ::: "memory");
        else            asm volatile("s_waitcnt vmcnt(0)" ::: "memory");
      }
      __builtin_amdgcn_s_barrier();
    }
  }

  // ---- epilogue: per-row sum of exp(logit) over 256 vocab cols ------------
  // 32x32 C/D: col = lane&31, row = (reg&3) + 8*(reg>>2) + 4*(lane>>5).
  // Undo the C*8 pre-scale: logit = acc * 0.125.
#pragma unroll
  for (int mi = 0; mi < 4; ++mi) {
    float p[16];
#pragma unroll
    for (int r = 0; r < 16; ++r)
      p[r] = __expf(acc[mi][0][r] * 0.125f) + __expf(acc[mi][1][r] * 0.125f);
#pragma unroll
    for (int m = 1; m < 32; m <<= 1)
#pragma unroll
      for (int r = 0; r < 16; ++r) p[r] += __shfl_xor(p[r], m, 64);
    if (l31 == 0) {
#pragma unroll
      for (int r = 0; r < 16; ++r) {
        const int row = brow + wr * 128 + mi * 32 + (r & 3) + 8 * (r >> 2) + 4 * lh;
        atomicAdd(&sumexp[row], p[r]);
      }
    }
  }
}

// ---------------- fallback path (fp32 reg-staged, 128^2 tile) --------------
#define FBM 128
#define FBN 128
#define FBK 64
#define FNK (DIM / FBK)
#define FTHREADS 512

__global__ __launch_bounds__(FTHREADS, 4)
void lce_gemm_f32(const float* __restrict__ E, const float* __restrict__ C,
                  float* __restrict__ sumexp) {
  extern __shared__ unsigned char lds[];
  const int tid  = threadIdx.x;
  const int brow = blockIdx.x * FBM;
  const int bcol = blockIdx.y * FBN;

  float4 ra[4], rb[4];
  auto ld = [&](int k0) {
#pragma unroll
    for (int i = 0; i < 4; ++i) {
      int f = tid + i * FTHREADS;
      int r = f >> 4;
      int c = (f & 15) << 2;
      ra[i] = *reinterpret_cast<const float4*>(&E[(size_t)(brow + r) * DIM + k0 + c]);
      rb[i] = *reinterpret_cast<const float4*>(&C[(size_t)(bcol + r) * DIM + k0 + c]);
    }
  };
  auto st = [&](int buf) {
    unsigned char* a = lds + buf * 32768;
    unsigned char* b = a + 16384;
#pragma unroll
    for (int i = 0; i < 4; ++i) {
      int f  = tid + i * FTHREADS;
      int r  = f >> 4;
      int cbb = (f & 15) << 3;
      int off = r * 128 + (cbb ^ ((r & 7) << 4));
      union { bf16_t h[4]; unsigned long long u; } pa, pb;
      pa.h[0] = (bf16_t)ra[i].x; pa.h[1] = (bf16_t)ra[i].y;
      pa.h[2] = (bf16_t)ra[i].z; pa.h[3] = (bf16_t)ra[i].w;
      pb.h[0] = (bf16_t)rb[i].x; pb.h[1] = (bf16_t)rb[i].y;
      pb.h[2] = (bf16_t)rb[i].z; pb.h[3] = (bf16_t)rb[i].w;
      *reinterpret_cast<unsigned long long*>(a + off) = pa.u;
      *reinterpret_cast<unsigned long long*>(b + off) = pb.u;
    }
  };

  f32x4 acc[4][2];
#pragma unroll
  for (int mi = 0; mi < 4; ++mi)
#pragma unroll
    for (int ni = 0; ni < 2; ++ni) acc[mi][ni] = (f32x4){0.f, 0.f, 0.f, 0.f};

  const int lane = tid & 63, wid = tid >> 6;
  const int wr = wid >> 2, wc = wid & 3;
  const int l15 = lane & 15, lg = lane >> 4;
  const int swz = (l15 & 7) << 4;

  auto comp = [&](int buf) {
    const unsigned char* a = lds + buf * 32768;
    const unsigned char* b = a + 16384;
#pragma unroll
    for (int kk = 0; kk < 2; ++kk) {
      const int cbase = (kk * 64 + lg * 16) ^ swz;
      bf16x8 af[4], bfr[2];
#pragma unroll
      for (int mi = 0; mi < 4; ++mi)
        af[mi] = *reinterpret_cast<const bf16x8*>(
            a + (wr * 64 + mi * 16 + l15) * 128 + cbase);
#pragma unroll
      for (int ni = 0; ni < 2; ++ni)
        bfr[ni] = *reinterpret_cast<const bf16x8*>(
            b + (wc * 32 + ni * 16 + l15) * 128 + cbase);
#pragma unroll
      for (int mi = 0; mi < 4; ++mi)
#pragma unroll
        for (int ni = 0; ni < 2; ++ni)
          acc[mi][ni] = __builtin_amdgcn_mfma_f32_16x16x32_bf16(
              af[mi], bfr[ni], acc[mi][ni], 0, 0, 0);
    }
  };

  ld(0);
  st(0);
  for (int kt = 0; kt < FNK; ++kt) {
    __syncthreads();
    if (kt + 1 < FNK) ld((kt + 1) * FBK);
    comp(kt & 1);
    if (kt + 1 < FNK) st((kt + 1) & 1);
  }

#pragma unroll
  for (int mi = 0; mi < 4; ++mi) {
    float p[4];
#pragma unroll
    for (int j = 0; j < 4; ++j)
      p[j] = __expf(acc[mi][0][j]) + __expf(acc[mi][1][j]);
#pragma unroll
    for (int m = 1; m < 16; m <<= 1)
#pragma unroll
      for (int j = 0; j < 4; ++j) p[j] += __shfl_xor(p[j], m, 64);
    if (l15 == 0) {
      int row = brow + wr * 64 + mi * 16 + lg * 4;
#pragma unroll
      for (int j = 0; j < 4; ++j) atomicAdd(&sumexp[row + j], p[j]);
    }
  }
}

// ---------------- exact fp32 target logit, one wave per row ----------------
__global__ __launch_bounds__(256)
void lce_tgt(const float* __restrict__ E, const float* __restrict__ C,
             const int* __restrict__ T, float* __restrict__ tgt) {
  int w = (int)((blockIdx.x * blockDim.x + threadIdx.x) >> 6);
  int lane = threadIdx.x & 63;
  if (w >= N_ROWS) return;
  int t = T[w];
  float s = 0.f;
  if (t != IGN) {
    const float4* er = reinterpret_cast<const float4*>(E + (size_t)w * DIM);
    const float4* cr = reinterpret_cast<const float4*>(C + (size_t)t * DIM);
#pragma unroll
    for (int i = 0; i < DIM / 4 / 64; ++i) {
      float4 a = er[lane + i * 64];
      float4 b = cr[lane + i * 64];
      s = fmaf(a.x, b.x, s); s = fmaf(a.y, b.y, s);
      s = fmaf(a.z, b.z, s); s = fmaf(a.w, b.w, s);
    }
#pragma unroll
    for (int m = 1; m < 64; m <<= 1) s += __shfl_xor(s, m, 64);
  }
  if (lane == 0) tgt[w] = s;
}

// ---------------- final scalar reduce --------------------------------------
__global__ __launch_bounds__(256)
void lce_finalize(const float* __restrict__ sumexp, const float* __restrict__ tgt,
                  const int* __restrict__ T, float* __restrict__ out) {
  int tid = threadIdx.x;
  float nll = 0.f, cnt = 0.f;
  for (int n = tid; n < N_ROWS; n += 256) {
    if (T[n] != IGN) {
      nll += logf(sumexp[n]) - tgt[n];
      cnt += 1.f;
    }
  }
#pragma unroll
  for (int m = 1; m < 64; m <<= 1) {
    nll += __shfl_xor(nll, m, 64);
    cnt += __shfl_xor(cnt, m, 64);
  }
  __shared__ float sn[4], sc[4];
  if ((tid & 63) == 0) { sn[tid >> 6] = nll; sc[tid >> 6] = cnt; }
  __syncthreads();
  if (tid == 0) {
    float a = 0.f, b = 0.f;
#pragma unroll
    for (int i = 0; i < 4; ++i) { a += sn[i]; b += sc[i]; }
    out[0] = a / fmaxf(b, 1.f);
  }
}

extern "C" void kernel_launch(void* const* d_in, const int* in_sizes, int n_in,
                              void* d_out, int out_size, void* d_ws, size_t ws_size,
                              hipStream_t stream) {
  const float* E = (const float*)d_in[0];
  const float* C = (const float*)d_in[1];
  const int*   T = (const int*)d_in[2];
  float* out = (float*)d_out;

  unsigned char* ws = (unsigned char*)d_ws;
  float* sumexp = (float*)ws;                        // 16 KB
  float* tgt    = (float*)(ws + 16384);              // 16 KB
  unsigned char* E8 = ws + 32768;                    // 8 MB
  unsigned char* C8 = E8 + (size_t)N_ROWS * DIM;     // 128 MB

  const size_t need = 32768 + (size_t)N_ROWS * DIM + (size_t)VOCAB * DIM;

  hipMemsetAsync(sumexp, 0, N_ROWS * sizeof(float), stream);

  if (ws_size >= need) {
    cvt_fp8<<<2048, 256, 0, stream>>>(E, E8, (long)N_ROWS * DIM / 16, 1.0f);
    cvt_fp8<<<2048, 256, 0, stream>>>(C, C8, (long)VOCAB * DIM / 16, 8.0f);
    lce_gemm_fp8<<<dim3((N_ROWS / BM) * (VOCAB / BN)), 512, 131072, stream>>>(E8, C8, sumexp);
  } else {
    lce_gemm_f32<<<dim3(N_ROWS / FBM, VOCAB / FBN), FTHREADS, 65536, stream>>>(E, C, sumexp);
  }

  lce_tgt<<<dim3((N_ROWS * 64) / 256), 256, 0, stream>>>(E, C, T, tgt);
  lce_finalize<<<dim3(1), 256, 0, stream>>>(sumexp, tgt, T, out);
}